// Round 1
// baseline (16024.467 us; speedup 1.0000x reference)
//
#include <hip/hip_runtime.h>
#include <math.h>

#define N_NODES 100000
#define N_EDGES 1600000
#define IN_DIM 128
#define HEADS 8
#define D1 16
#define D2 8
#define NEG_SLOPE 0.2f

// ---------------------------------------------------------------------------
// GEMM: C[n_rows, OUTC] = A[n_rows, K] @ W[K, OUTC]
// One thread per output element; W columns coalesced across threads; A row
// broadcast within a wave (uniform address -> single request).
// ---------------------------------------------------------------------------
template<int K, int OUTC>
__global__ void gemm_kernel(const float* __restrict__ A, const float* __restrict__ W,
                            float* __restrict__ C, int n_rows) {
    constexpr int RPB = 256 / OUTC;
    int tid = threadIdx.x;
    int r = tid / OUTC;
    int j = tid % OUTC;
    int n = blockIdx.x * RPB + r;
    if (n >= n_rows) return;
    const float* a = A + (long)n * K;
    float acc = 0.f;
#pragma unroll
    for (int c = 0; c < K; ++c) {
        acc = fmaf(a[c], W[c * OUTC + j], acc);
    }
    C[(long)n * OUTC + j] = acc;
}

// ---------------------------------------------------------------------------
// Attention scores: s_src[n,h] = <h[n,h,:], a_src[h,:]>, same for dst.
// One thread per (node, head).
// ---------------------------------------------------------------------------
template<int D>
__global__ void scores_kernel(const float* __restrict__ h,
                              const float* __restrict__ a_src,
                              const float* __restrict__ a_dst,
                              float* __restrict__ s_src,
                              float* __restrict__ s_dst) {
    int i = blockIdx.x * blockDim.x + threadIdx.x;   // over N_NODES*HEADS
    if (i >= N_NODES * HEADS) return;
    int hd = i % HEADS;
    const float* hp = h + (long)i * D;
    float ss = 0.f, sd = 0.f;
#pragma unroll
    for (int k = 0; k < D; ++k) {
        float v = hp[k];
        ss = fmaf(v, a_src[hd * D + k], ss);
        sd = fmaf(v, a_dst[hd * D + k], sd);
    }
    s_src[i] = ss;
    s_dst[i] = sd;
}

// ---------------------------------------------------------------------------
// Edge pass: for each (edge, head): w = exp(leakyrelu(s_src[s]+s_dst[d]))
// (no max-subtraction: scores are O(1), exp cannot overflow; softmax is
// shift-invariant so result matches reference), then scatter-accumulate
// denom and weighted source features with fp32 atomics.
// Edges e >= N_EDGES are the self-loops (s = d = e - N_EDGES).
// ---------------------------------------------------------------------------
template<int D>
__global__ void edge_kernel(const int* __restrict__ src, const int* __restrict__ dst,
                            const float* __restrict__ h,
                            const float* __restrict__ ssrc,
                            const float* __restrict__ sdst,
                            float* __restrict__ den, float* __restrict__ agg,
                            int n_edges_total) {
    long i = (long)blockIdx.x * blockDim.x + threadIdx.x;  // over n_edges_total*HEADS
    if (i >= (long)n_edges_total * HEADS) return;
    int e  = (int)(i >> 3);        // HEADS == 8
    int hd = (int)(i & 7);
    int s, d;
    if (e < N_EDGES) { s = src[e]; d = dst[e]; }
    else             { s = e - N_EDGES; d = s; }
    float sc = ssrc[s * HEADS + hd] + sdst[d * HEADS + hd];
    float el = sc > 0.f ? sc : NEG_SLOPE * sc;
    float w = __expf(el);
    atomicAdd(&den[d * HEADS + hd], w);
    const float* hp = h + ((long)s * HEADS + hd) * D;
    float* ap = agg + ((long)d * HEADS + hd) * D;
#pragma unroll
    for (int k = 0; k < D; ++k) {
        atomicAdd(&ap[k], w * hp[k]);
    }
}

// ---------------------------------------------------------------------------
// Finalize layer 1 (in place on agg): v = relu(agg/(den+eps) + b)
// ---------------------------------------------------------------------------
__global__ void finalize1_kernel(float* __restrict__ agg, const float* __restrict__ den,
                                 const float* __restrict__ b) {
    int i = blockIdx.x * blockDim.x + threadIdx.x;   // over N_NODES*128
    if (i >= N_NODES * HEADS * D1) return;
    int f  = i & (HEADS * D1 - 1);     // i % 128
    int n  = i >> 7;                   // i / 128
    int hd = f >> 4;                   // f / 16
    float v = agg[i] / (den[n * HEADS + hd] + 1e-16f) + b[f];
    agg[i] = v > 0.f ? v : 0.f;
}

// ---------------------------------------------------------------------------
// Finalize layer 2 -> d_out: v = agg/(den+eps) + b  (no relu)
// ---------------------------------------------------------------------------
__global__ void finalize2_kernel(const float* __restrict__ agg, const float* __restrict__ den,
                                 const float* __restrict__ b, float* __restrict__ out) {
    int i = blockIdx.x * blockDim.x + threadIdx.x;   // over N_NODES*64
    if (i >= N_NODES * HEADS * D2) return;
    int f  = i & (HEADS * D2 - 1);     // i % 64
    int n  = i >> 6;                   // i / 64
    int hd = f >> 3;                   // f / 8
    out[i] = agg[i] / (den[n * HEADS + hd] + 1e-16f) + b[f];
}

extern "C" void kernel_launch(void* const* d_in, const int* in_sizes, int n_in,
                              void* d_out, int out_size, void* d_ws, size_t ws_size,
                              hipStream_t stream) {
    const float* x   = (const float*)d_in[0];
    const int*   ei  = (const int*)d_in[1];      // [2, N_EDGES] row-major
    const float* W1  = (const float*)d_in[2];
    const float* a1s = (const float*)d_in[3];
    const float* a1d = (const float*)d_in[4];
    const float* b1  = (const float*)d_in[5];
    const float* W2  = (const float*)d_in[6];
    const float* a2s = (const float*)d_in[7];
    const float* a2d = (const float*)d_in[8];
    const float* b2  = (const float*)d_in[9];
    float* out = (float*)d_out;

    const int* src = ei;
    const int* dst = ei + N_EDGES;

    float* ws = (float*)d_ws;
    float* bufA = ws;                                 // N*128 : h1, later h2 + agg2
    float* bufB = ws + (size_t)N_NODES * 128;         // N*128 : agg1 -> out1 (in place)
    float* ssrc = bufB + (size_t)N_NODES * 128;       // N*8
    float* sdst = ssrc + (size_t)N_NODES * HEADS;     // N*8
    float* den  = sdst + (size_t)N_NODES * HEADS;     // N*8

    const int n_edges_total = N_EDGES + N_NODES;      // real edges + self loops
    const long ew = (long)n_edges_total * HEADS;
    const int edge_blocks = (int)((ew + 255) / 256);

    // ---- Layer 1 ----
    hipMemsetAsync(bufB, 0, (size_t)N_NODES * 128 * sizeof(float), stream);
    hipMemsetAsync(den,  0, (size_t)N_NODES * HEADS * sizeof(float), stream);

    gemm_kernel<128, 128><<<(N_NODES + 1) / 2, 256, 0, stream>>>(x, W1, bufA, N_NODES);
    scores_kernel<D1><<<(N_NODES * HEADS + 255) / 256, 256, 0, stream>>>(bufA, a1s, a1d, ssrc, sdst);
    edge_kernel<D1><<<edge_blocks, 256, 0, stream>>>(src, dst, bufA, ssrc, sdst, den, bufB, n_edges_total);
    finalize1_kernel<<<(N_NODES * 128 + 255) / 256, 256, 0, stream>>>(bufB, den, b1);

    // ---- Layer 2 ----
    // h2 = out1 @ W2  (out1 = bufB, h2 -> bufA[0 : N*64])
    gemm_kernel<128, 64><<<(N_NODES + 3) / 4, 256, 0, stream>>>(bufB, W2, bufA, N_NODES);
    scores_kernel<D2><<<(N_NODES * HEADS + 255) / 256, 256, 0, stream>>>(bufA, a2s, a2d, ssrc, sdst);

    float* agg2 = bufA + (size_t)N_NODES * 64;
    hipMemsetAsync(agg2, 0, (size_t)N_NODES * 64 * sizeof(float), stream);
    hipMemsetAsync(den,  0, (size_t)N_NODES * HEADS * sizeof(float), stream);

    edge_kernel<D2><<<edge_blocks, 256, 0, stream>>>(src, dst, bufA, ssrc, sdst, den, agg2, n_edges_total);
    finalize2_kernel<<<(N_NODES * 64 + 255) / 256, 256, 0, stream>>>(agg2, den, b2, out);
}

// Round 2
// 1147.154 us; speedup vs baseline: 13.9689x; 13.9689x over previous
//
#include <hip/hip_runtime.h>
#include <math.h>

#define N_NODES 100000
#define N_EDGES 1600000
#define IN_DIM 128
#define HEADS 8
#define D1 16
#define D2 8
#define NEG_SLOPE 0.2f

// ---------------------------------------------------------------------------
// GEMM: C[n_rows, OUTC] = A[n_rows, K] @ W[K, OUTC], float4-vectorized.
// Each thread computes 4 adjacent output columns for one row.
// A-row reads are wave-broadcast (uniform within the row's thread group),
// W reads coalesced float4, W is L2-resident (<=64 KB).
// ---------------------------------------------------------------------------
template<int K, int OUTC>
__global__ void gemm_v4_kernel(const float* __restrict__ A, const float* __restrict__ W,
                               float* __restrict__ C, int n_rows) {
    constexpr int JT = OUTC / 4;       // threads per row
    constexpr int RPB = 256 / JT;      // rows per block
    int tid = threadIdx.x;
    int n = blockIdx.x * RPB + tid / JT;
    int j4 = tid % JT;
    if (n >= n_rows) return;
    const float4* a4 = (const float4*)(A + (long)n * K);
    const float* wp = W + j4 * 4;
    float4 acc = make_float4(0.f, 0.f, 0.f, 0.f);
#pragma unroll
    for (int c4 = 0; c4 < K / 4; ++c4) {
        float4 av = a4[c4];
        float4 w0 = *(const float4*)(wp + (c4 * 4 + 0) * OUTC);
        float4 w1 = *(const float4*)(wp + (c4 * 4 + 1) * OUTC);
        float4 w2 = *(const float4*)(wp + (c4 * 4 + 2) * OUTC);
        float4 w3 = *(const float4*)(wp + (c4 * 4 + 3) * OUTC);
        acc.x = fmaf(av.x, w0.x, acc.x); acc.y = fmaf(av.x, w0.y, acc.y);
        acc.z = fmaf(av.x, w0.z, acc.z); acc.w = fmaf(av.x, w0.w, acc.w);
        acc.x = fmaf(av.y, w1.x, acc.x); acc.y = fmaf(av.y, w1.y, acc.y);
        acc.z = fmaf(av.y, w1.z, acc.z); acc.w = fmaf(av.y, w1.w, acc.w);
        acc.x = fmaf(av.z, w2.x, acc.x); acc.y = fmaf(av.z, w2.y, acc.y);
        acc.z = fmaf(av.z, w2.z, acc.z); acc.w = fmaf(av.z, w2.w, acc.w);
        acc.x = fmaf(av.w, w3.x, acc.x); acc.y = fmaf(av.w, w3.y, acc.y);
        acc.z = fmaf(av.w, w3.z, acc.z); acc.w = fmaf(av.w, w3.w, acc.w);
    }
    *(float4*)(C + (long)n * OUTC + j4 * 4) = acc;
}

// ---------------------------------------------------------------------------
// Attention scores: s_src[n,h] = <h[n,h,:], a_src[h,:]>, same for dst.
// ---------------------------------------------------------------------------
template<int D>
__global__ void scores_kernel(const float* __restrict__ h,
                              const float* __restrict__ a_src,
                              const float* __restrict__ a_dst,
                              float* __restrict__ s_src,
                              float* __restrict__ s_dst) {
    int i = blockIdx.x * blockDim.x + threadIdx.x;   // over N_NODES*HEADS
    if (i >= N_NODES * HEADS) return;
    int hd = i % HEADS;
    const float* hp = h + (long)i * D;
    float ss = 0.f, sd = 0.f;
#pragma unroll
    for (int k = 0; k < D; ++k) {
        float v = hp[k];
        ss = fmaf(v, a_src[hd * D + k], ss);
        sd = fmaf(v, a_dst[hd * D + k], sd);
    }
    s_src[i] = ss;
    s_dst[i] = sd;
}

// ---------------------------------------------------------------------------
// CSR build: count -> block scan -> scan of block sums -> add offsets -> scatter
// ---------------------------------------------------------------------------
__global__ void count_kernel(const int* __restrict__ dst, int* __restrict__ counts) {
    int e = blockIdx.x * blockDim.x + threadIdx.x;
    if (e < N_EDGES) atomicAdd(&counts[dst[e]], 1);
}

__global__ void scan_block_kernel(const int* __restrict__ counts, int* __restrict__ rs,
                                  int* __restrict__ bsums, int n) {
    __shared__ int sh[256];
    int tid = threadIdx.x;
    int base = blockIdx.x * 1024 + tid * 4;
    int c0 = (base + 0 < n) ? counts[base + 0] : 0;
    int c1 = (base + 1 < n) ? counts[base + 1] : 0;
    int c2 = (base + 2 < n) ? counts[base + 2] : 0;
    int c3 = (base + 3 < n) ? counts[base + 3] : 0;
    int p1 = c0, p2 = c0 + c1, p3 = c0 + c1 + c2, tot = c0 + c1 + c2 + c3;
    sh[tid] = tot;
    __syncthreads();
    int run = tot;
    for (int off = 1; off < 256; off <<= 1) {
        int add = (tid >= off) ? sh[tid - off] : 0;
        __syncthreads();
        run += add;
        sh[tid] = run;
        __syncthreads();
    }
    int excl = run - tot;
    if (base + 0 < n) rs[base + 0] = excl;
    if (base + 1 < n) rs[base + 1] = excl + p1;
    if (base + 2 < n) rs[base + 2] = excl + p2;
    if (base + 3 < n) rs[base + 3] = excl + p3;
    if (tid == 255) bsums[blockIdx.x] = run;   // block total
}

__global__ void scan_sums_kernel(int* __restrict__ bsums, int nb) {
    if (blockIdx.x == 0 && threadIdx.x == 0) {
        int run = 0;
        for (int i = 0; i < nb; ++i) { int c = bsums[i]; bsums[i] = run; run += c; }
    }
}

__global__ void add_offsets_kernel(int* __restrict__ rs, const int* __restrict__ bsums,
                                   int* __restrict__ cursor, int n) {
    int tid = threadIdx.x;
    int base = blockIdx.x * 1024 + tid * 4;
    int add = bsums[blockIdx.x];
#pragma unroll
    for (int j = 0; j < 4; ++j) {
        int i = base + j;
        if (i < n) { int v = rs[i] + add; rs[i] = v; cursor[i] = v; }
    }
    if (blockIdx.x == 0 && tid == 0) rs[n] = N_EDGES;
}

__global__ void scatter_kernel(const int* __restrict__ src, const int* __restrict__ dst,
                               int* __restrict__ cursor, int* __restrict__ eidx) {
    int e = blockIdx.x * blockDim.x + threadIdx.x;
    if (e >= N_EDGES) return;
    int d = dst[e];
    int pos = atomicAdd(&cursor[d], 1);
    eidx[pos] = src[e];
}

// ---------------------------------------------------------------------------
// Fused aggregation + softmax + finalize. One thread per (dst, head, k):
// register accumulation over the node's CSR segment, no atomics, no denom
// array. Self-loop handled implicitly (every node). exp recomputed per lane
// (D-way redundant) — far cheaper than any cross-lane traffic.
// ---------------------------------------------------------------------------
template<int D, bool RELU>
__global__ void aggregate_kernel(const int* __restrict__ rs, const int* __restrict__ eidx,
                                 const float* __restrict__ h,
                                 const float* __restrict__ ssrc, const float* __restrict__ sdst,
                                 const float* __restrict__ bias, float* __restrict__ out) {
    constexpr int F = HEADS * D;       // 128 or 64
    constexpr int NPB = 256 / F;       // nodes per block
    int tid = threadIdx.x;
    int node = blockIdx.x * NPB + tid / F;
    if (node >= N_NODES) return;
    int f = tid % F;
    int hd = f / D;
    float sd = sdst[node * HEADS + hd];
    // self-loop contribution
    float sc = ssrc[node * HEADS + hd] + sd;
    float w = __expf(sc > 0.f ? sc : NEG_SLOPE * sc);
    float wsum = w;
    float acc = w * h[(long)node * F + f];
    int e0 = rs[node], e1 = rs[node + 1];
    for (int e = e0; e < e1; ++e) {
        int s = eidx[e];
        float sc2 = ssrc[s * HEADS + hd] + sd;
        float el = sc2 > 0.f ? sc2 : NEG_SLOPE * sc2;
        float we = __expf(el);
        wsum += we;
        acc = fmaf(we, h[(long)s * F + f], acc);
    }
    float v = acc / (wsum + 1e-16f) + bias[f];
    if (RELU) v = v > 0.f ? v : 0.f;
    out[(long)node * F + f] = v;
}

extern "C" void kernel_launch(void* const* d_in, const int* in_sizes, int n_in,
                              void* d_out, int out_size, void* d_ws, size_t ws_size,
                              hipStream_t stream) {
    const float* x   = (const float*)d_in[0];
    const int*   ei  = (const int*)d_in[1];      // [2, N_EDGES] row-major
    const float* W1  = (const float*)d_in[2];
    const float* a1s = (const float*)d_in[3];
    const float* a1d = (const float*)d_in[4];
    const float* b1  = (const float*)d_in[5];
    const float* W2  = (const float*)d_in[6];
    const float* a2s = (const float*)d_in[7];
    const float* a2d = (const float*)d_in[8];
    const float* b2  = (const float*)d_in[9];
    float* out = (float*)d_out;

    const int* src = ei;
    const int* dst = ei + N_EDGES;

    // ---- workspace layout ----
    float* ws = (float*)d_ws;
    float* bufA = ws;                                  // N*128 : h1, later h2 (N*64)
    float* bufB = bufA + (size_t)N_NODES * 128;        // N*128 : out1
    float* ssrc = bufB + (size_t)N_NODES * 128;        // N*8
    float* sdst = ssrc + (size_t)N_NODES * HEADS;      // N*8
    int* counts    = (int*)(sdst + (size_t)N_NODES * HEADS);  // N
    int* row_start = counts + N_NODES;                 // N+1
    int* cursor    = row_start + N_NODES + 1;          // N
    int* bsums     = cursor + N_NODES;                 // 128
    int* eidx      = bsums + 128;                      // N_EDGES

    const int nb_scan = (N_NODES + 1023) / 1024;       // 98

    // ---- CSR build (shared by both layers) ----
    hipMemsetAsync(counts, 0, (size_t)N_NODES * sizeof(int), stream);
    count_kernel<<<(N_EDGES + 255) / 256, 256, 0, stream>>>(dst, counts);
    scan_block_kernel<<<nb_scan, 256, 0, stream>>>(counts, row_start, bsums, N_NODES);
    scan_sums_kernel<<<1, 64, 0, stream>>>(bsums, nb_scan);
    add_offsets_kernel<<<nb_scan, 256, 0, stream>>>(row_start, bsums, cursor, N_NODES);
    scatter_kernel<<<(N_EDGES + 255) / 256, 256, 0, stream>>>(src, dst, cursor, eidx);

    // ---- Layer 1 ----
    gemm_v4_kernel<128, 128><<<(N_NODES + 7) / 8, 256, 0, stream>>>(x, W1, bufA, N_NODES);
    scores_kernel<D1><<<(N_NODES * HEADS + 255) / 256, 256, 0, stream>>>(bufA, a1s, a1d, ssrc, sdst);
    aggregate_kernel<D1, true><<<(N_NODES + 1) / 2, 256, 0, stream>>>(
        row_start, eidx, bufA, ssrc, sdst, b1, bufB);

    // ---- Layer 2 ----
    gemm_v4_kernel<128, 64><<<(N_NODES + 15) / 16, 256, 0, stream>>>(bufB, W2, bufA, N_NODES);
    scores_kernel<D2><<<(N_NODES * HEADS + 255) / 256, 256, 0, stream>>>(bufA, a2s, a2d, ssrc, sdst);
    aggregate_kernel<D2, false><<<(N_NODES + 3) / 4, 256, 0, stream>>>(
        row_start, eidx, bufA, ssrc, sdst, b2, out);
}

// Round 3
// 896.089 us; speedup vs baseline: 17.8827x; 1.2802x over previous
//
#include <hip/hip_runtime.h>
#include <math.h>

#define N_NODES 100000
#define N_EDGES 1600000
#define IN_DIM 128
#define HEADS 8
#define D1 16
#define D2 8
#define NEG_SLOPE 0.2f

// ---------------------------------------------------------------------------
// GEMM: C[n_rows, OUTC] = A[n_rows, K] @ W[K, OUTC], float4-vectorized.
// ---------------------------------------------------------------------------
template<int K, int OUTC>
__global__ void gemm_v4_kernel(const float* __restrict__ A, const float* __restrict__ W,
                               float* __restrict__ C, int n_rows) {
    constexpr int JT = OUTC / 4;       // threads per row
    constexpr int RPB = 256 / JT;      // rows per block
    int tid = threadIdx.x;
    int n = blockIdx.x * RPB + tid / JT;
    int j4 = tid % JT;
    if (n >= n_rows) return;
    const float4* a4 = (const float4*)(A + (long)n * K);
    const float* wp = W + j4 * 4;
    float4 acc = make_float4(0.f, 0.f, 0.f, 0.f);
#pragma unroll
    for (int c4 = 0; c4 < K / 4; ++c4) {
        float4 av = a4[c4];
        float4 w0 = *(const float4*)(wp + (c4 * 4 + 0) * OUTC);
        float4 w1 = *(const float4*)(wp + (c4 * 4 + 1) * OUTC);
        float4 w2 = *(const float4*)(wp + (c4 * 4 + 2) * OUTC);
        float4 w3 = *(const float4*)(wp + (c4 * 4 + 3) * OUTC);
        acc.x = fmaf(av.x, w0.x, acc.x); acc.y = fmaf(av.x, w0.y, acc.y);
        acc.z = fmaf(av.x, w0.z, acc.z); acc.w = fmaf(av.x, w0.w, acc.w);
        acc.x = fmaf(av.y, w1.x, acc.x); acc.y = fmaf(av.y, w1.y, acc.y);
        acc.z = fmaf(av.y, w1.z, acc.z); acc.w = fmaf(av.y, w1.w, acc.w);
        acc.x = fmaf(av.z, w2.x, acc.x); acc.y = fmaf(av.z, w2.y, acc.y);
        acc.z = fmaf(av.z, w2.z, acc.z); acc.w = fmaf(av.z, w2.w, acc.w);
        acc.x = fmaf(av.w, w3.x, acc.x); acc.y = fmaf(av.w, w3.y, acc.y);
        acc.z = fmaf(av.w, w3.z, acc.z); acc.w = fmaf(av.w, w3.w, acc.w);
    }
    *(float4*)(C + (long)n * OUTC + j4 * 4) = acc;
}

// ---------------------------------------------------------------------------
// Attention scores: one thread per (node, head); float4 loads of the D-vec.
// ---------------------------------------------------------------------------
template<int D>
__global__ void scores_kernel(const float* __restrict__ h,
                              const float* __restrict__ a_src,
                              const float* __restrict__ a_dst,
                              float* __restrict__ s_src,
                              float* __restrict__ s_dst) {
    int i = blockIdx.x * blockDim.x + threadIdx.x;   // over N_NODES*HEADS
    if (i >= N_NODES * HEADS) return;
    int hd = i & 7;
    const float4* hp = (const float4*)(h + (long)i * D);
    const float4* as = (const float4*)(a_src + hd * D);
    const float4* ad = (const float4*)(a_dst + hd * D);
    float ss = 0.f, sd = 0.f;
#pragma unroll
    for (int r = 0; r < D / 4; ++r) {
        float4 v = hp[r], s4 = as[r], d4 = ad[r];
        ss = fmaf(v.x, s4.x, ss); ss = fmaf(v.y, s4.y, ss);
        ss = fmaf(v.z, s4.z, ss); ss = fmaf(v.w, s4.w, ss);
        sd = fmaf(v.x, d4.x, sd); sd = fmaf(v.y, d4.y, sd);
        sd = fmaf(v.z, d4.z, sd); sd = fmaf(v.w, d4.w, sd);
    }
    s_src[i] = ss;
    s_dst[i] = sd;
}

// ---------------------------------------------------------------------------
// CSR build: count -> block scan -> scan of block sums -> add offsets -> scatter
// ---------------------------------------------------------------------------
__global__ void count_kernel(const int* __restrict__ dst, int* __restrict__ counts) {
    int e = blockIdx.x * blockDim.x + threadIdx.x;
    if (e < N_EDGES) atomicAdd(&counts[dst[e]], 1);
}

__global__ void scan_block_kernel(const int* __restrict__ counts, int* __restrict__ rs,
                                  int* __restrict__ bsums, int n) {
    __shared__ int sh[256];
    int tid = threadIdx.x;
    int base = blockIdx.x * 1024 + tid * 4;
    int c0 = (base + 0 < n) ? counts[base + 0] : 0;
    int c1 = (base + 1 < n) ? counts[base + 1] : 0;
    int c2 = (base + 2 < n) ? counts[base + 2] : 0;
    int c3 = (base + 3 < n) ? counts[base + 3] : 0;
    int p1 = c0, p2 = c0 + c1, p3 = c0 + c1 + c2, tot = c0 + c1 + c2 + c3;
    sh[tid] = tot;
    __syncthreads();
    int run = tot;
    for (int off = 1; off < 256; off <<= 1) {
        int add = (tid >= off) ? sh[tid - off] : 0;
        __syncthreads();
        run += add;
        sh[tid] = run;
        __syncthreads();
    }
    int excl = run - tot;
    if (base + 0 < n) rs[base + 0] = excl;
    if (base + 1 < n) rs[base + 1] = excl + p1;
    if (base + 2 < n) rs[base + 2] = excl + p2;
    if (base + 3 < n) rs[base + 3] = excl + p3;
    if (tid == 255) bsums[blockIdx.x] = run;   // block total
}

__global__ void scan_sums_kernel(int* __restrict__ bsums, int nb) {
    if (blockIdx.x == 0 && threadIdx.x == 0) {
        int run = 0;
        for (int i = 0; i < nb; ++i) { int c = bsums[i]; bsums[i] = run; run += c; }
    }
}

__global__ void add_offsets_kernel(int* __restrict__ rs, const int* __restrict__ bsums,
                                   int* __restrict__ cursor, int n) {
    int tid = threadIdx.x;
    int base = blockIdx.x * 1024 + tid * 4;
    int add = bsums[blockIdx.x];
#pragma unroll
    for (int j = 0; j < 4; ++j) {
        int i = base + j;
        if (i < n) { int v = rs[i] + add; rs[i] = v; cursor[i] = v; }
    }
    if (blockIdx.x == 0 && tid == 0) rs[n] = N_EDGES;
}

__global__ void scatter_kernel(const int* __restrict__ src, const int* __restrict__ dst,
                               int* __restrict__ cursor, int* __restrict__ eidx) {
    int e = blockIdx.x * blockDim.x + threadIdx.x;
    if (e >= N_EDGES) return;
    int d = dst[e];
    int pos = atomicAdd(&cursor[d], 1);
    eidx[pos] = src[e];
}

// ---------------------------------------------------------------------------
// Fused aggregation + softmax + finalize. One thread per (dst, head) holding
// all D features in float4 registers. Per edge: uniform eidx load, coalesced
// 4B score load, one exp (no D-way redundancy), D/4 float4 gathers, D FMAs.
// Self-loop folded into the accumulator init. No atomics, no denom array.
// ---------------------------------------------------------------------------
template<int D, bool RELU>
__global__ void aggregate_kernel(const int* __restrict__ rs, const int* __restrict__ eidx,
                                 const float* __restrict__ h,
                                 const float* __restrict__ ssrc, const float* __restrict__ sdst,
                                 const float* __restrict__ bias, float* __restrict__ out) {
    constexpr int F = HEADS * D;       // 128 or 64
    constexpr int R = D / 4;           // float4s per thread
    int t = blockIdx.x * blockDim.x + threadIdx.x;   // over N_NODES*HEADS
    if (t >= N_NODES * HEADS) return;
    int node = t >> 3;
    int hd = t & 7;

    float sd = sdst[t];
    // self-loop contribution
    float sc = ssrc[t] + sd;
    float w = __expf(sc > 0.f ? sc : NEG_SLOPE * sc);
    float wsum = w;
    float4 acc[R];
    const float4* hp = (const float4*)(h + (long)node * F + hd * D);
#pragma unroll
    for (int r = 0; r < R; ++r) {
        float4 v = hp[r];
        acc[r] = make_float4(w * v.x, w * v.y, w * v.z, w * v.w);
    }

    int e0 = rs[node], e1 = rs[node + 1];
    for (int e = e0; e < e1; ++e) {
        int s = eidx[e];
        float sc2 = ssrc[s * HEADS + hd] + sd;
        float el = sc2 > 0.f ? sc2 : NEG_SLOPE * sc2;
        float we = __expf(el);
        wsum += we;
        const float4* sp = (const float4*)(h + (long)s * F + hd * D);
#pragma unroll
        for (int r = 0; r < R; ++r) {
            float4 v = sp[r];
            acc[r].x = fmaf(we, v.x, acc[r].x);
            acc[r].y = fmaf(we, v.y, acc[r].y);
            acc[r].z = fmaf(we, v.z, acc[r].z);
            acc[r].w = fmaf(we, v.w, acc[r].w);
        }
    }

    float inv = 1.f / (wsum + 1e-16f);
    float4* op = (float4*)(out + (long)node * F + hd * D);
#pragma unroll
    for (int r = 0; r < R; ++r) {
        const float4* bp = (const float4*)(bias + hd * D + r * 4);
        float4 b4 = *bp;
        float4 v;
        v.x = acc[r].x * inv + b4.x;
        v.y = acc[r].y * inv + b4.y;
        v.z = acc[r].z * inv + b4.z;
        v.w = acc[r].w * inv + b4.w;
        if (RELU) {
            v.x = v.x > 0.f ? v.x : 0.f;
            v.y = v.y > 0.f ? v.y : 0.f;
            v.z = v.z > 0.f ? v.z : 0.f;
            v.w = v.w > 0.f ? v.w : 0.f;
        }
        op[r] = v;
    }
}

extern "C" void kernel_launch(void* const* d_in, const int* in_sizes, int n_in,
                              void* d_out, int out_size, void* d_ws, size_t ws_size,
                              hipStream_t stream) {
    const float* x   = (const float*)d_in[0];
    const int*   ei  = (const int*)d_in[1];      // [2, N_EDGES] row-major
    const float* W1  = (const float*)d_in[2];
    const float* a1s = (const float*)d_in[3];
    const float* a1d = (const float*)d_in[4];
    const float* b1  = (const float*)d_in[5];
    const float* W2  = (const float*)d_in[6];
    const float* a2s = (const float*)d_in[7];
    const float* a2d = (const float*)d_in[8];
    const float* b2  = (const float*)d_in[9];
    float* out = (float*)d_out;

    const int* src = ei;
    const int* dst = ei + N_EDGES;

    // ---- workspace layout ----
    float* ws = (float*)d_ws;
    float* bufA = ws;                                  // N*128 : h1, later h2 (N*64)
    float* bufB = bufA + (size_t)N_NODES * 128;        // N*128 : out1
    float* ssrc = bufB + (size_t)N_NODES * 128;        // N*8
    float* sdst = ssrc + (size_t)N_NODES * HEADS;      // N*8
    int* counts    = (int*)(sdst + (size_t)N_NODES * HEADS);  // N
    int* row_start = counts + N_NODES;                 // N+1
    int* cursor    = row_start + N_NODES + 1;          // N
    int* bsums     = cursor + N_NODES;                 // 128
    int* eidx      = bsums + 128;                      // N_EDGES

    const int nb_scan = (N_NODES + 1023) / 1024;       // 98

    // ---- CSR build (shared by both layers) ----
    hipMemsetAsync(counts, 0, (size_t)N_NODES * sizeof(int), stream);
    count_kernel<<<(N_EDGES + 255) / 256, 256, 0, stream>>>(dst, counts);
    scan_block_kernel<<<nb_scan, 256, 0, stream>>>(counts, row_start, bsums, N_NODES);
    scan_sums_kernel<<<1, 64, 0, stream>>>(bsums, nb_scan);
    add_offsets_kernel<<<nb_scan, 256, 0, stream>>>(row_start, bsums, cursor, N_NODES);
    scatter_kernel<<<(N_EDGES + 255) / 256, 256, 0, stream>>>(src, dst, cursor, eidx);

    // ---- Layer 1 ----
    gemm_v4_kernel<128, 128><<<(N_NODES + 7) / 8, 256, 0, stream>>>(x, W1, bufA, N_NODES);
    scores_kernel<D1><<<(N_NODES * HEADS + 255) / 256, 256, 0, stream>>>(bufA, a1s, a1d, ssrc, sdst);
    aggregate_kernel<D1, true><<<(N_NODES * HEADS + 255) / 256, 256, 0, stream>>>(
        row_start, eidx, bufA, ssrc, sdst, b1, bufB);

    // ---- Layer 2 ----
    gemm_v4_kernel<128, 64><<<(N_NODES + 15) / 16, 256, 0, stream>>>(bufB, W2, bufA, N_NODES);
    scores_kernel<D2><<<(N_NODES * HEADS + 255) / 256, 256, 0, stream>>>(bufA, a2s, a2d, ssrc, sdst);
    aggregate_kernel<D2, false><<<(N_NODES * HEADS + 255) / 256, 256, 0, stream>>>(
        row_start, eidx, bufA, ssrc, sdst, b2, out);
}

// Round 4
// 824.829 us; speedup vs baseline: 19.4276x; 1.0864x over previous
//
#include <hip/hip_runtime.h>
#include <math.h>

#define N_NODES 100000
#define N_EDGES 1600000
#define IN_DIM 128
#define HEADS 8
#define D1 16
#define D2 8
#define NEG_SLOPE 0.2f

// ---------------------------------------------------------------------------
// Register-tiled GEMM: C[n_rows, OUTC] = A[n_rows, K] @ W[K, OUTC].
// Each thread computes an 8x8 output tile: per c4-iteration 16 float4 loads
// feed 256 lane-FMAs (1:16 load:fma ratio, vs 1:3.2 for the naive version).
// OUTC=128: 16x16 thread grid -> 128 rows x 128 cols per block.
// OUTC=64 :  32x8 thread grid -> 256 rows x  64 cols per block.
// Row overrun handled by clamping read rows (valid addrs) + predicated stores.
// ---------------------------------------------------------------------------
template<int K, int OUTC>
__global__ void gemm_tile_kernel(const float* __restrict__ A, const float* __restrict__ W,
                                 float* __restrict__ C, int n_rows) {
    constexpr int CT = OUTC / 8;       // col-threads per row group
    constexpr int RT = 256 / CT;       // row-threads
    constexpr int BM = RT * 8;         // rows per block
    int tid = threadIdx.x;
    int ct = tid % CT;
    int rt = tid / CT;
    int row0 = blockIdx.x * BM + rt * 8;
    int col0 = ct * 8;

    const float* ap[8];
#pragma unroll
    for (int r = 0; r < 8; ++r) {
        int rr = row0 + r;
        rr = rr < n_rows ? rr : n_rows - 1;   // clamp: keep address valid
        ap[r] = A + (long)rr * K;
    }

    float4 acc[8][2];
#pragma unroll
    for (int r = 0; r < 8; ++r) {
        acc[r][0] = make_float4(0.f, 0.f, 0.f, 0.f);
        acc[r][1] = make_float4(0.f, 0.f, 0.f, 0.f);
    }

    const float* wp = W + col0;
#pragma unroll 4
    for (int c4 = 0; c4 < K / 4; ++c4) {
        float4 a[8];
#pragma unroll
        for (int r = 0; r < 8; ++r) a[r] = *(const float4*)(ap[r] + c4 * 4);
        float4 w0[4], w1[4];
#pragma unroll
        for (int k = 0; k < 4; ++k) {
            const float* wk = wp + (c4 * 4 + k) * OUTC;
            w0[k] = *(const float4*)(wk);
            w1[k] = *(const float4*)(wk + 4);
        }
#pragma unroll
        for (int r = 0; r < 8; ++r) {
            float as[4] = {a[r].x, a[r].y, a[r].z, a[r].w};
#pragma unroll
            for (int k = 0; k < 4; ++k) {
                float av = as[k];
                acc[r][0].x = fmaf(av, w0[k].x, acc[r][0].x);
                acc[r][0].y = fmaf(av, w0[k].y, acc[r][0].y);
                acc[r][0].z = fmaf(av, w0[k].z, acc[r][0].z);
                acc[r][0].w = fmaf(av, w0[k].w, acc[r][0].w);
                acc[r][1].x = fmaf(av, w1[k].x, acc[r][1].x);
                acc[r][1].y = fmaf(av, w1[k].y, acc[r][1].y);
                acc[r][1].z = fmaf(av, w1[k].z, acc[r][1].z);
                acc[r][1].w = fmaf(av, w1[k].w, acc[r][1].w);
            }
        }
    }

#pragma unroll
    for (int r = 0; r < 8; ++r) {
        int rr = row0 + r;
        if (rr < n_rows) {
            float* cp = C + (long)rr * OUTC + col0;
            *(float4*)(cp)     = acc[r][0];
            *(float4*)(cp + 4) = acc[r][1];
        }
    }
}

// ---------------------------------------------------------------------------
// Attention scores: one thread per (node, head); float4 loads of the D-vec.
// ---------------------------------------------------------------------------
template<int D>
__global__ void scores_kernel(const float* __restrict__ h,
                              const float* __restrict__ a_src,
                              const float* __restrict__ a_dst,
                              float* __restrict__ s_src,
                              float* __restrict__ s_dst) {
    int i = blockIdx.x * blockDim.x + threadIdx.x;   // over N_NODES*HEADS
    if (i >= N_NODES * HEADS) return;
    int hd = i & 7;
    const float4* hp = (const float4*)(h + (long)i * D);
    const float4* as = (const float4*)(a_src + hd * D);
    const float4* ad = (const float4*)(a_dst + hd * D);
    float ss = 0.f, sd = 0.f;
#pragma unroll
    for (int r = 0; r < D / 4; ++r) {
        float4 v = hp[r], s4 = as[r], d4 = ad[r];
        ss = fmaf(v.x, s4.x, ss); ss = fmaf(v.y, s4.y, ss);
        ss = fmaf(v.z, s4.z, ss); ss = fmaf(v.w, s4.w, ss);
        sd = fmaf(v.x, d4.x, sd); sd = fmaf(v.y, d4.y, sd);
        sd = fmaf(v.z, d4.z, sd); sd = fmaf(v.w, d4.w, sd);
    }
    s_src[i] = ss;
    s_dst[i] = sd;
}

// ---------------------------------------------------------------------------
// CSR build: count -> block scan -> scan of block sums -> add offsets -> scatter
// ---------------------------------------------------------------------------
__global__ void count_kernel(const int* __restrict__ dst, int* __restrict__ counts) {
    int e = blockIdx.x * blockDim.x + threadIdx.x;
    if (e < N_EDGES) atomicAdd(&counts[dst[e]], 1);
}

__global__ void scan_block_kernel(const int* __restrict__ counts, int* __restrict__ rs,
                                  int* __restrict__ bsums, int n) {
    __shared__ int sh[256];
    int tid = threadIdx.x;
    int base = blockIdx.x * 1024 + tid * 4;
    int c0 = (base + 0 < n) ? counts[base + 0] : 0;
    int c1 = (base + 1 < n) ? counts[base + 1] : 0;
    int c2 = (base + 2 < n) ? counts[base + 2] : 0;
    int c3 = (base + 3 < n) ? counts[base + 3] : 0;
    int p1 = c0, p2 = c0 + c1, p3 = c0 + c1 + c2, tot = c0 + c1 + c2 + c3;
    sh[tid] = tot;
    __syncthreads();
    int run = tot;
    for (int off = 1; off < 256; off <<= 1) {
        int add = (tid >= off) ? sh[tid - off] : 0;
        __syncthreads();
        run += add;
        sh[tid] = run;
        __syncthreads();
    }
    int excl = run - tot;
    if (base + 0 < n) rs[base + 0] = excl;
    if (base + 1 < n) rs[base + 1] = excl + p1;
    if (base + 2 < n) rs[base + 2] = excl + p2;
    if (base + 3 < n) rs[base + 3] = excl + p3;
    if (tid == 255) bsums[blockIdx.x] = run;   // block total
}

__global__ void scan_sums_kernel(int* __restrict__ bsums, int nb) {
    if (blockIdx.x == 0 && threadIdx.x == 0) {
        int run = 0;
        for (int i = 0; i < nb; ++i) { int c = bsums[i]; bsums[i] = run; run += c; }
    }
}

__global__ void add_offsets_kernel(int* __restrict__ rs, const int* __restrict__ bsums,
                                   int* __restrict__ cursor, int n) {
    int tid = threadIdx.x;
    int base = blockIdx.x * 1024 + tid * 4;
    int add = bsums[blockIdx.x];
#pragma unroll
    for (int j = 0; j < 4; ++j) {
        int i = base + j;
        if (i < n) { int v = rs[i] + add; rs[i] = v; cursor[i] = v; }
    }
    if (blockIdx.x == 0 && tid == 0) rs[n] = N_EDGES;
}

__global__ void scatter_kernel(const int* __restrict__ src, const int* __restrict__ dst,
                               int* __restrict__ cursor, int* __restrict__ eidx) {
    int e = blockIdx.x * blockDim.x + threadIdx.x;
    if (e >= N_EDGES) return;
    int d = dst[e];
    int pos = atomicAdd(&cursor[d], 1);
    eidx[pos] = src[e];
}

// ---------------------------------------------------------------------------
// Fused aggregation + softmax + finalize. One thread per (dst, head) holding
// all D features in float4 registers.
// ---------------------------------------------------------------------------
template<int D, bool RELU>
__global__ void aggregate_kernel(const int* __restrict__ rs, const int* __restrict__ eidx,
                                 const float* __restrict__ h,
                                 const float* __restrict__ ssrc, const float* __restrict__ sdst,
                                 const float* __restrict__ bias, float* __restrict__ out) {
    constexpr int F = HEADS * D;       // 128 or 64
    constexpr int R = D / 4;           // float4s per thread
    int t = blockIdx.x * blockDim.x + threadIdx.x;   // over N_NODES*HEADS
    if (t >= N_NODES * HEADS) return;
    int node = t >> 3;
    int hd = t & 7;

    float sd = sdst[t];
    // self-loop contribution
    float sc = ssrc[t] + sd;
    float w = __expf(sc > 0.f ? sc : NEG_SLOPE * sc);
    float wsum = w;
    float4 acc[R];
    const float4* hp = (const float4*)(h + (long)node * F + hd * D);
#pragma unroll
    for (int r = 0; r < R; ++r) {
        float4 v = hp[r];
        acc[r] = make_float4(w * v.x, w * v.y, w * v.z, w * v.w);
    }

    int e0 = rs[node], e1 = rs[node + 1];
    for (int e = e0; e < e1; ++e) {
        int s = eidx[e];
        float sc2 = ssrc[s * HEADS + hd] + sd;
        float el = sc2 > 0.f ? sc2 : NEG_SLOPE * sc2;
        float we = __expf(el);
        wsum += we;
        const float4* sp = (const float4*)(h + (long)s * F + hd * D);
#pragma unroll
        for (int r = 0; r < R; ++r) {
            float4 v = sp[r];
            acc[r].x = fmaf(we, v.x, acc[r].x);
            acc[r].y = fmaf(we, v.y, acc[r].y);
            acc[r].z = fmaf(we, v.z, acc[r].z);
            acc[r].w = fmaf(we, v.w, acc[r].w);
        }
    }

    float inv = 1.f / (wsum + 1e-16f);
    float4* op = (float4*)(out + (long)node * F + hd * D);
#pragma unroll
    for (int r = 0; r < R; ++r) {
        const float4* bp = (const float4*)(bias + hd * D + r * 4);
        float4 b4 = *bp;
        float4 v;
        v.x = acc[r].x * inv + b4.x;
        v.y = acc[r].y * inv + b4.y;
        v.z = acc[r].z * inv + b4.z;
        v.w = acc[r].w * inv + b4.w;
        if (RELU) {
            v.x = v.x > 0.f ? v.x : 0.f;
            v.y = v.y > 0.f ? v.y : 0.f;
            v.z = v.z > 0.f ? v.z : 0.f;
            v.w = v.w > 0.f ? v.w : 0.f;
        }
        op[r] = v;
    }
}

extern "C" void kernel_launch(void* const* d_in, const int* in_sizes, int n_in,
                              void* d_out, int out_size, void* d_ws, size_t ws_size,
                              hipStream_t stream) {
    const float* x   = (const float*)d_in[0];
    const int*   ei  = (const int*)d_in[1];      // [2, N_EDGES] row-major
    const float* W1  = (const float*)d_in[2];
    const float* a1s = (const float*)d_in[3];
    const float* a1d = (const float*)d_in[4];
    const float* b1  = (const float*)d_in[5];
    const float* W2  = (const float*)d_in[6];
    const float* a2s = (const float*)d_in[7];
    const float* a2d = (const float*)d_in[8];
    const float* b2  = (const float*)d_in[9];
    float* out = (float*)d_out;

    const int* src = ei;
    const int* dst = ei + N_EDGES;

    // ---- workspace layout ----
    float* ws = (float*)d_ws;
    float* bufA = ws;                                  // N*128 : h1, later h2 (N*64)
    float* bufB = bufA + (size_t)N_NODES * 128;        // N*128 : out1
    float* ssrc = bufB + (size_t)N_NODES * 128;        // N*8
    float* sdst = ssrc + (size_t)N_NODES * HEADS;      // N*8
    int* counts    = (int*)(sdst + (size_t)N_NODES * HEADS);  // N
    int* row_start = counts + N_NODES;                 // N+1
    int* cursor    = row_start + N_NODES + 1;          // N
    int* bsums     = cursor + N_NODES;                 // 128
    int* eidx      = bsums + 128;                      // N_EDGES

    const int nb_scan = (N_NODES + 1023) / 1024;       // 98

    // ---- CSR build (shared by both layers) ----
    hipMemsetAsync(counts, 0, (size_t)N_NODES * sizeof(int), stream);
    count_kernel<<<(N_EDGES + 255) / 256, 256, 0, stream>>>(dst, counts);
    scan_block_kernel<<<nb_scan, 256, 0, stream>>>(counts, row_start, bsums, N_NODES);
    scan_sums_kernel<<<1, 64, 0, stream>>>(bsums, nb_scan);
    add_offsets_kernel<<<nb_scan, 256, 0, stream>>>(row_start, bsums, cursor, N_NODES);
    scatter_kernel<<<(N_EDGES + 255) / 256, 256, 0, stream>>>(src, dst, cursor, eidx);

    // ---- Layer 1 ----
    gemm_tile_kernel<128, 128><<<(N_NODES + 127) / 128, 256, 0, stream>>>(x, W1, bufA, N_NODES);
    scores_kernel<D1><<<(N_NODES * HEADS + 255) / 256, 256, 0, stream>>>(bufA, a1s, a1d, ssrc, sdst);
    aggregate_kernel<D1, true><<<(N_NODES * HEADS + 255) / 256, 256, 0, stream>>>(
        row_start, eidx, bufA, ssrc, sdst, b1, bufB);

    // ---- Layer 2 ----
    gemm_tile_kernel<128, 64><<<(N_NODES + 255) / 256, 256, 0, stream>>>(bufB, W2, bufA, N_NODES);
    scores_kernel<D2><<<(N_NODES * HEADS + 255) / 256, 256, 0, stream>>>(bufA, a2s, a2d, ssrc, sdst);
    aggregate_kernel<D2, false><<<(N_NODES * HEADS + 255) / 256, 256, 0, stream>>>(
        row_start, eidx, bufA, ssrc, sdst, b2, out);
}

// Round 5
// 769.311 us; speedup vs baseline: 20.8296x; 1.0722x over previous
//
#include <hip/hip_runtime.h>
#include <math.h>

#define N_NODES 100000
#define N_EDGES 1600000
#define IN_DIM 128
#define HEADS 8
#define D1 16
#define D2 8
#define NEG_SLOPE 0.2f

// ---------------------------------------------------------------------------
// Register-tiled GEMM: C[n_rows, OUTC] = A[n_rows, K] @ W[K, OUTC].
// Each thread computes an 8x8 output tile: per c4-iteration 16 float4 loads
// feed 256 lane-FMAs (1:16 load:fma ratio).
// __launch_bounds__(256): without it the compiler assumes 1024-thread
// workgroups and caps the allocation at 64 VGPRs -> the 64 accumulator
// registers spill to scratch (R4 counters: WRITE_SIZE 163 MB vs 51 MB
// logical). With it, acc stays in registers.
// ---------------------------------------------------------------------------
template<int K, int OUTC>
__global__ __launch_bounds__(256)
void gemm_tile_kernel(const float* __restrict__ A, const float* __restrict__ W,
                      float* __restrict__ C, int n_rows) {
    constexpr int CT = OUTC / 8;       // col-threads per row group
    constexpr int RT = 256 / CT;       // row-threads
    constexpr int BM = RT * 8;         // rows per block
    int tid = threadIdx.x;
    int ct = tid % CT;
    int rt = tid / CT;
    int row0 = blockIdx.x * BM + rt * 8;
    int col0 = ct * 8;

    const float* ap[8];
#pragma unroll
    for (int r = 0; r < 8; ++r) {
        int rr = row0 + r;
        rr = rr < n_rows ? rr : n_rows - 1;   // clamp: keep address valid
        ap[r] = A + (long)rr * K;
    }

    float4 acc[8][2];
#pragma unroll
    for (int r = 0; r < 8; ++r) {
        acc[r][0] = make_float4(0.f, 0.f, 0.f, 0.f);
        acc[r][1] = make_float4(0.f, 0.f, 0.f, 0.f);
    }

    const float* wp = W + col0;
#pragma unroll 4
    for (int c4 = 0; c4 < K / 4; ++c4) {
        float4 a[8];
#pragma unroll
        for (int r = 0; r < 8; ++r) a[r] = *(const float4*)(ap[r] + c4 * 4);
        float4 w0[4], w1[4];
#pragma unroll
        for (int k = 0; k < 4; ++k) {
            const float* wk = wp + (c4 * 4 + k) * OUTC;
            w0[k] = *(const float4*)(wk);
            w1[k] = *(const float4*)(wk + 4);
        }
#pragma unroll
        for (int r = 0; r < 8; ++r) {
            float as[4] = {a[r].x, a[r].y, a[r].z, a[r].w};
#pragma unroll
            for (int k = 0; k < 4; ++k) {
                float av = as[k];
                acc[r][0].x = fmaf(av, w0[k].x, acc[r][0].x);
                acc[r][0].y = fmaf(av, w0[k].y, acc[r][0].y);
                acc[r][0].z = fmaf(av, w0[k].z, acc[r][0].z);
                acc[r][0].w = fmaf(av, w0[k].w, acc[r][0].w);
                acc[r][1].x = fmaf(av, w1[k].x, acc[r][1].x);
                acc[r][1].y = fmaf(av, w1[k].y, acc[r][1].y);
                acc[r][1].z = fmaf(av, w1[k].z, acc[r][1].z);
                acc[r][1].w = fmaf(av, w1[k].w, acc[r][1].w);
            }
        }
    }

#pragma unroll
    for (int r = 0; r < 8; ++r) {
        int rr = row0 + r;
        if (rr < n_rows) {
            float* cp = C + (long)rr * OUTC + col0;
            *(float4*)(cp)     = acc[r][0];
            *(float4*)(cp + 4) = acc[r][1];
        }
    }
}

// ---------------------------------------------------------------------------
// Attention scores: one thread per (node, head); float4 loads of the D-vec.
// ---------------------------------------------------------------------------
template<int D>
__global__ void scores_kernel(const float* __restrict__ h,
                              const float* __restrict__ a_src,
                              const float* __restrict__ a_dst,
                              float* __restrict__ s_src,
                              float* __restrict__ s_dst) {
    int i = blockIdx.x * blockDim.x + threadIdx.x;   // over N_NODES*HEADS
    if (i >= N_NODES * HEADS) return;
    int hd = i & 7;
    const float4* hp = (const float4*)(h + (long)i * D);
    const float4* as = (const float4*)(a_src + hd * D);
    const float4* ad = (const float4*)(a_dst + hd * D);
    float ss = 0.f, sd = 0.f;
#pragma unroll
    for (int r = 0; r < D / 4; ++r) {
        float4 v = hp[r], s4 = as[r], d4 = ad[r];
        ss = fmaf(v.x, s4.x, ss); ss = fmaf(v.y, s4.y, ss);
        ss = fmaf(v.z, s4.z, ss); ss = fmaf(v.w, s4.w, ss);
        sd = fmaf(v.x, d4.x, sd); sd = fmaf(v.y, d4.y, sd);
        sd = fmaf(v.z, d4.z, sd); sd = fmaf(v.w, d4.w, sd);
    }
    s_src[i] = ss;
    s_dst[i] = sd;
}

// ---------------------------------------------------------------------------
// CSR build: count -> block scan -> scan of block sums -> add offsets -> scatter
// ---------------------------------------------------------------------------
__global__ void count_kernel(const int* __restrict__ dst, int* __restrict__ counts) {
    int e = blockIdx.x * blockDim.x + threadIdx.x;
    if (e < N_EDGES) atomicAdd(&counts[dst[e]], 1);
}

__global__ void scan_block_kernel(const int* __restrict__ counts, int* __restrict__ rs,
                                  int* __restrict__ bsums, int n) {
    __shared__ int sh[256];
    int tid = threadIdx.x;
    int base = blockIdx.x * 1024 + tid * 4;
    int c0 = (base + 0 < n) ? counts[base + 0] : 0;
    int c1 = (base + 1 < n) ? counts[base + 1] : 0;
    int c2 = (base + 2 < n) ? counts[base + 2] : 0;
    int c3 = (base + 3 < n) ? counts[base + 3] : 0;
    int p1 = c0, p2 = c0 + c1, p3 = c0 + c1 + c2, tot = c0 + c1 + c2 + c3;
    sh[tid] = tot;
    __syncthreads();
    int run = tot;
    for (int off = 1; off < 256; off <<= 1) {
        int add = (tid >= off) ? sh[tid - off] : 0;
        __syncthreads();
        run += add;
        sh[tid] = run;
        __syncthreads();
    }
    int excl = run - tot;
    if (base + 0 < n) rs[base + 0] = excl;
    if (base + 1 < n) rs[base + 1] = excl + p1;
    if (base + 2 < n) rs[base + 2] = excl + p2;
    if (base + 3 < n) rs[base + 3] = excl + p3;
    if (tid == 255) bsums[blockIdx.x] = run;   // block total
}

__global__ void scan_sums_kernel(int* __restrict__ bsums, int nb) {
    if (blockIdx.x == 0 && threadIdx.x == 0) {
        int run = 0;
        for (int i = 0; i < nb; ++i) { int c = bsums[i]; bsums[i] = run; run += c; }
    }
}

__global__ void add_offsets_kernel(int* __restrict__ rs, const int* __restrict__ bsums,
                                   int* __restrict__ cursor, int n) {
    int tid = threadIdx.x;
    int base = blockIdx.x * 1024 + tid * 4;
    int add = bsums[blockIdx.x];
#pragma unroll
    for (int j = 0; j < 4; ++j) {
        int i = base + j;
        if (i < n) { int v = rs[i] + add; rs[i] = v; cursor[i] = v; }
    }
    if (blockIdx.x == 0 && tid == 0) rs[n] = N_EDGES;
}

__global__ void scatter_kernel(const int* __restrict__ src, const int* __restrict__ dst,
                               int* __restrict__ cursor, int* __restrict__ eidx) {
    int e = blockIdx.x * blockDim.x + threadIdx.x;
    if (e >= N_EDGES) return;
    int d = dst[e];
    int pos = atomicAdd(&cursor[d], 1);
    eidx[pos] = src[e];
}

// ---------------------------------------------------------------------------
// Fused aggregation + softmax + finalize. One thread per (dst, head) holding
// all D features in float4 registers.
// ---------------------------------------------------------------------------
template<int D, bool RELU>
__global__ void aggregate_kernel(const int* __restrict__ rs, const int* __restrict__ eidx,
                                 const float* __restrict__ h,
                                 const float* __restrict__ ssrc, const float* __restrict__ sdst,
                                 const float* __restrict__ bias, float* __restrict__ out) {
    constexpr int F = HEADS * D;       // 128 or 64
    constexpr int R = D / 4;           // float4s per thread
    int t = blockIdx.x * blockDim.x + threadIdx.x;   // over N_NODES*HEADS
    if (t >= N_NODES * HEADS) return;
    int node = t >> 3;
    int hd = t & 7;

    float sd = sdst[t];
    // self-loop contribution
    float sc = ssrc[t] + sd;
    float w = __expf(sc > 0.f ? sc : NEG_SLOPE * sc);
    float wsum = w;
    float4 acc[R];
    const float4* hp = (const float4*)(h + (long)node * F + hd * D);
#pragma unroll
    for (int r = 0; r < R; ++r) {
        float4 v = hp[r];
        acc[r] = make_float4(w * v.x, w * v.y, w * v.z, w * v.w);
    }

    int e0 = rs[node], e1 = rs[node + 1];
    for (int e = e0; e < e1; ++e) {
        int s = eidx[e];
        float sc2 = ssrc[s * HEADS + hd] + sd;
        float el = sc2 > 0.f ? sc2 : NEG_SLOPE * sc2;
        float we = __expf(el);
        wsum += we;
        const float4* sp = (const float4*)(h + (long)s * F + hd * D);
#pragma unroll
        for (int r = 0; r < R; ++r) {
            float4 v = sp[r];
            acc[r].x = fmaf(we, v.x, acc[r].x);
            acc[r].y = fmaf(we, v.y, acc[r].y);
            acc[r].z = fmaf(we, v.z, acc[r].z);
            acc[r].w = fmaf(we, v.w, acc[r].w);
        }
    }

    float inv = 1.f / (wsum + 1e-16f);
    float4* op = (float4*)(out + (long)node * F + hd * D);
#pragma unroll
    for (int r = 0; r < R; ++r) {
        const float4* bp = (const float4*)(bias + hd * D + r * 4);
        float4 b4 = *bp;
        float4 v;
        v.x = acc[r].x * inv + b4.x;
        v.y = acc[r].y * inv + b4.y;
        v.z = acc[r].z * inv + b4.z;
        v.w = acc[r].w * inv + b4.w;
        if (RELU) {
            v.x = v.x > 0.f ? v.x : 0.f;
            v.y = v.y > 0.f ? v.y : 0.f;
            v.z = v.z > 0.f ? v.z : 0.f;
            v.w = v.w > 0.f ? v.w : 0.f;
        }
        op[r] = v;
    }
}

extern "C" void kernel_launch(void* const* d_in, const int* in_sizes, int n_in,
                              void* d_out, int out_size, void* d_ws, size_t ws_size,
                              hipStream_t stream) {
    const float* x   = (const float*)d_in[0];
    const int*   ei  = (const int*)d_in[1];      // [2, N_EDGES] row-major
    const float* W1  = (const float*)d_in[2];
    const float* a1s = (const float*)d_in[3];
    const float* a1d = (const float*)d_in[4];
    const float* b1  = (const float*)d_in[5];
    const float* W2  = (const float*)d_in[6];
    const float* a2s = (const float*)d_in[7];
    const float* a2d = (const float*)d_in[8];
    const float* b2  = (const float*)d_in[9];
    float* out = (float*)d_out;

    const int* src = ei;
    const int* dst = ei + N_EDGES;

    // ---- workspace layout ----
    float* ws = (float*)d_ws;
    float* bufA = ws;                                  // N*128 : h1, later h2 (N*64)
    float* bufB = bufA + (size_t)N_NODES * 128;        // N*128 : out1
    float* ssrc = bufB + (size_t)N_NODES * 128;        // N*8
    float* sdst = ssrc + (size_t)N_NODES * HEADS;      // N*8
    int* counts    = (int*)(sdst + (size_t)N_NODES * HEADS);  // N
    int* row_start = counts + N_NODES;                 // N+1
    int* cursor    = row_start + N_NODES + 1;          // N
    int* bsums     = cursor + N_NODES;                 // 128
    int* eidx      = bsums + 128;                      // N_EDGES

    const int nb_scan = (N_NODES + 1023) / 1024;       // 98

    // ---- CSR build (shared by both layers) ----
    hipMemsetAsync(counts, 0, (size_t)N_NODES * sizeof(int), stream);
    count_kernel<<<(N_EDGES + 255) / 256, 256, 0, stream>>>(dst, counts);
    scan_block_kernel<<<nb_scan, 256, 0, stream>>>(counts, row_start, bsums, N_NODES);
    scan_sums_kernel<<<1, 64, 0, stream>>>(bsums, nb_scan);
    add_offsets_kernel<<<nb_scan, 256, 0, stream>>>(row_start, bsums, cursor, N_NODES);
    scatter_kernel<<<(N_EDGES + 255) / 256, 256, 0, stream>>>(src, dst, cursor, eidx);

    // ---- Layer 1 ----
    gemm_tile_kernel<128, 128><<<(N_NODES + 127) / 128, 256, 0, stream>>>(x, W1, bufA, N_NODES);
    scores_kernel<D1><<<(N_NODES * HEADS + 255) / 256, 256, 0, stream>>>(bufA, a1s, a1d, ssrc, sdst);
    aggregate_kernel<D1, true><<<(N_NODES * HEADS + 255) / 256, 256, 0, stream>>>(
        row_start, eidx, bufA, ssrc, sdst, b1, bufB);

    // ---- Layer 2 ----
    gemm_tile_kernel<128, 64><<<(N_NODES + 255) / 256, 256, 0, stream>>>(bufB, W2, bufA, N_NODES);
    scores_kernel<D2><<<(N_NODES * HEADS + 255) / 256, 256, 0, stream>>>(bufA, a2s, a2d, ssrc, sdst);
    aggregate_kernel<D2, false><<<(N_NODES * HEADS + 255) / 256, 256, 0, stream>>>(
        row_start, eidx, bufA, ssrc, sdst, b2, out);
}

// Round 6
// 743.890 us; speedup vs baseline: 21.5414x; 1.0342x over previous
//
#include <hip/hip_runtime.h>
#include <math.h>

#define N_NODES 100000
#define N_EDGES 1600000
#define IN_DIM 128
#define HEADS 8
#define D1 16
#define D2 8
#define NEG_SLOPE 0.2f

// ---------------------------------------------------------------------------
// Register-tiled GEMM: C[n_rows, OUTC] = A[n_rows, K] @ W[K, OUTC].
// 8x8 output tile per thread; __launch_bounds__(256) so the 64 accumulator
// VGPRs don't spill (R4: without it, 163 MB of spill-store traffic).
// ---------------------------------------------------------------------------
template<int K, int OUTC>
__global__ __launch_bounds__(256)
void gemm_tile_kernel(const float* __restrict__ A, const float* __restrict__ W,
                      float* __restrict__ C, int n_rows) {
    constexpr int CT = OUTC / 8;       // col-threads per row group
    constexpr int RT = 256 / CT;       // row-threads
    constexpr int BM = RT * 8;         // rows per block
    int tid = threadIdx.x;
    int ct = tid % CT;
    int rt = tid / CT;
    int row0 = blockIdx.x * BM + rt * 8;
    int col0 = ct * 8;

    const float* ap[8];
#pragma unroll
    for (int r = 0; r < 8; ++r) {
        int rr = row0 + r;
        rr = rr < n_rows ? rr : n_rows - 1;   // clamp: keep address valid
        ap[r] = A + (long)rr * K;
    }

    float4 acc[8][2];
#pragma unroll
    for (int r = 0; r < 8; ++r) {
        acc[r][0] = make_float4(0.f, 0.f, 0.f, 0.f);
        acc[r][1] = make_float4(0.f, 0.f, 0.f, 0.f);
    }

    const float* wp = W + col0;
#pragma unroll 4
    for (int c4 = 0; c4 < K / 4; ++c4) {
        float4 a[8];
#pragma unroll
        for (int r = 0; r < 8; ++r) a[r] = *(const float4*)(ap[r] + c4 * 4);
        float4 w0[4], w1[4];
#pragma unroll
        for (int k = 0; k < 4; ++k) {
            const float* wk = wp + (c4 * 4 + k) * OUTC;
            w0[k] = *(const float4*)(wk);
            w1[k] = *(const float4*)(wk + 4);
        }
#pragma unroll
        for (int r = 0; r < 8; ++r) {
            float as[4] = {a[r].x, a[r].y, a[r].z, a[r].w};
#pragma unroll
            for (int k = 0; k < 4; ++k) {
                float av = as[k];
                acc[r][0].x = fmaf(av, w0[k].x, acc[r][0].x);
                acc[r][0].y = fmaf(av, w0[k].y, acc[r][0].y);
                acc[r][0].z = fmaf(av, w0[k].z, acc[r][0].z);
                acc[r][0].w = fmaf(av, w0[k].w, acc[r][0].w);
                acc[r][1].x = fmaf(av, w1[k].x, acc[r][1].x);
                acc[r][1].y = fmaf(av, w1[k].y, acc[r][1].y);
                acc[r][1].z = fmaf(av, w1[k].z, acc[r][1].z);
                acc[r][1].w = fmaf(av, w1[k].w, acc[r][1].w);
            }
        }
    }

#pragma unroll
    for (int r = 0; r < 8; ++r) {
        int rr = row0 + r;
        if (rr < n_rows) {
            float* cp = C + (long)rr * OUTC + col0;
            *(float4*)(cp)     = acc[r][0];
            *(float4*)(cp + 4) = acc[r][1];
        }
    }
}

// ---------------------------------------------------------------------------
// Attention scores: one thread per (node, head); float4 loads of the D-vec.
// ---------------------------------------------------------------------------
template<int D>
__global__ void scores_kernel(const float* __restrict__ h,
                              const float* __restrict__ a_src,
                              const float* __restrict__ a_dst,
                              float* __restrict__ s_src,
                              float* __restrict__ s_dst) {
    int i = blockIdx.x * blockDim.x + threadIdx.x;   // over N_NODES*HEADS
    if (i >= N_NODES * HEADS) return;
    int hd = i & 7;
    const float4* hp = (const float4*)(h + (long)i * D);
    const float4* as = (const float4*)(a_src + hd * D);
    const float4* ad = (const float4*)(a_dst + hd * D);
    float ss = 0.f, sd = 0.f;
#pragma unroll
    for (int r = 0; r < D / 4; ++r) {
        float4 v = hp[r], s4 = as[r], d4 = ad[r];
        ss = fmaf(v.x, s4.x, ss); ss = fmaf(v.y, s4.y, ss);
        ss = fmaf(v.z, s4.z, ss); ss = fmaf(v.w, s4.w, ss);
        sd = fmaf(v.x, d4.x, sd); sd = fmaf(v.y, d4.y, sd);
        sd = fmaf(v.z, d4.z, sd); sd = fmaf(v.w, d4.w, sd);
    }
    s_src[i] = ss;
    s_dst[i] = sd;
}

// ---------------------------------------------------------------------------
// CSR build: count -> block scan -> scan of block sums -> add offsets -> scatter
// ---------------------------------------------------------------------------
__global__ void count_kernel(const int* __restrict__ dst, int* __restrict__ counts) {
    int e = blockIdx.x * blockDim.x + threadIdx.x;
    if (e < N_EDGES) atomicAdd(&counts[dst[e]], 1);
}

__global__ void scan_block_kernel(const int* __restrict__ counts, int* __restrict__ rs,
                                  int* __restrict__ bsums, int n) {
    __shared__ int sh[256];
    int tid = threadIdx.x;
    int base = blockIdx.x * 1024 + tid * 4;
    int c0 = (base + 0 < n) ? counts[base + 0] : 0;
    int c1 = (base + 1 < n) ? counts[base + 1] : 0;
    int c2 = (base + 2 < n) ? counts[base + 2] : 0;
    int c3 = (base + 3 < n) ? counts[base + 3] : 0;
    int p1 = c0, p2 = c0 + c1, p3 = c0 + c1 + c2, tot = c0 + c1 + c2 + c3;
    sh[tid] = tot;
    __syncthreads();
    int run = tot;
    for (int off = 1; off < 256; off <<= 1) {
        int add = (tid >= off) ? sh[tid - off] : 0;
        __syncthreads();
        run += add;
        sh[tid] = run;
        __syncthreads();
    }
    int excl = run - tot;
    if (base + 0 < n) rs[base + 0] = excl;
    if (base + 1 < n) rs[base + 1] = excl + p1;
    if (base + 2 < n) rs[base + 2] = excl + p2;
    if (base + 3 < n) rs[base + 3] = excl + p3;
    if (tid == 255) bsums[blockIdx.x] = run;   // block total
}

__global__ void scan_sums_kernel(int* __restrict__ bsums, int nb) {
    if (blockIdx.x == 0 && threadIdx.x == 0) {
        int run = 0;
        for (int i = 0; i < nb; ++i) { int c = bsums[i]; bsums[i] = run; run += c; }
    }
}

__global__ void add_offsets_kernel(int* __restrict__ rs, const int* __restrict__ bsums,
                                   int* __restrict__ cursor, int n) {
    int tid = threadIdx.x;
    int base = blockIdx.x * 1024 + tid * 4;
    int add = bsums[blockIdx.x];
#pragma unroll
    for (int j = 0; j < 4; ++j) {
        int i = base + j;
        if (i < n) { int v = rs[i] + add; rs[i] = v; cursor[i] = v; }
    }
    if (blockIdx.x == 0 && tid == 0) rs[n] = N_EDGES;
}

__global__ void scatter_kernel(const int* __restrict__ src, const int* __restrict__ dst,
                               int* __restrict__ cursor, int* __restrict__ eidx) {
    int e = blockIdx.x * blockDim.x + threadIdx.x;
    if (e >= N_EDGES) return;
    int d = dst[e];
    int pos = atomicAdd(&cursor[d], 1);
    eidx[pos] = src[e];
}

// ---------------------------------------------------------------------------
// Fused aggregation + softmax + finalize. One thread per (dst, head), all D
// features in float4 registers. Edge loop unrolled by 4 with batched loads:
// all 4 edges' eidx/ssrc/h-row loads are issued before any consumption, so
// each wave keeps ~4x more memory requests in flight (R5 showed the loop was
// latency-bound: VALUBusy 8%, 1 load issued per 90 cycles per CU).
// ---------------------------------------------------------------------------
template<int D, bool RELU>
__global__ __launch_bounds__(256)
void aggregate_kernel(const int* __restrict__ rs, const int* __restrict__ eidx,
                      const float* __restrict__ h,
                      const float* __restrict__ ssrc, const float* __restrict__ sdst,
                      const float* __restrict__ bias, float* __restrict__ out) {
    constexpr int F = HEADS * D;       // 128 or 64
    constexpr int R = D / 4;           // float4s per thread
    int t = blockIdx.x * blockDim.x + threadIdx.x;   // over N_NODES*HEADS
    if (t >= N_NODES * HEADS) return;
    int node = t >> 3;
    int hd = t & 7;

    float sd = sdst[t];
    // self-loop contribution
    float sc = ssrc[t] + sd;
    float w = __expf(sc > 0.f ? sc : NEG_SLOPE * sc);
    float wsum = w;
    float4 acc[R];
    const float4* hp = (const float4*)(h + (long)node * F + hd * D);
#pragma unroll
    for (int r = 0; r < R; ++r) {
        float4 v = hp[r];
        acc[r] = make_float4(w * v.x, w * v.y, w * v.z, w * v.w);
    }

    int e0 = rs[node], e1 = rs[node + 1];
    int e = e0;

    // ---- unroll-by-4 with batched loads ----
    for (; e + 4 <= e1; e += 4) {
        int s0 = eidx[e + 0];
        int s1 = eidx[e + 1];
        int s2 = eidx[e + 2];
        int s3 = eidx[e + 3];
        float c0 = ssrc[s0 * HEADS + hd];
        float c1 = ssrc[s1 * HEADS + hd];
        float c2 = ssrc[s2 * HEADS + hd];
        float c3 = ssrc[s3 * HEADS + hd];
        const float4* p0 = (const float4*)(h + (long)s0 * F + hd * D);
        const float4* p1 = (const float4*)(h + (long)s1 * F + hd * D);
        const float4* p2 = (const float4*)(h + (long)s2 * F + hd * D);
        const float4* p3 = (const float4*)(h + (long)s3 * F + hd * D);
        float4 v0[R], v1[R], v2[R], v3[R];
#pragma unroll
        for (int r = 0; r < R; ++r) { v0[r] = p0[r]; v1[r] = p1[r]; v2[r] = p2[r]; v3[r] = p3[r]; }

        float t0 = c0 + sd, t1 = c1 + sd, t2 = c2 + sd, t3 = c3 + sd;
        float w0 = __expf(t0 > 0.f ? t0 : NEG_SLOPE * t0);
        float w1 = __expf(t1 > 0.f ? t1 : NEG_SLOPE * t1);
        float w2 = __expf(t2 > 0.f ? t2 : NEG_SLOPE * t2);
        float w3 = __expf(t3 > 0.f ? t3 : NEG_SLOPE * t3);
        wsum += (w0 + w1) + (w2 + w3);
#pragma unroll
        for (int r = 0; r < R; ++r) {
            acc[r].x = fmaf(w0, v0[r].x, acc[r].x);
            acc[r].y = fmaf(w0, v0[r].y, acc[r].y);
            acc[r].z = fmaf(w0, v0[r].z, acc[r].z);
            acc[r].w = fmaf(w0, v0[r].w, acc[r].w);
            acc[r].x = fmaf(w1, v1[r].x, acc[r].x);
            acc[r].y = fmaf(w1, v1[r].y, acc[r].y);
            acc[r].z = fmaf(w1, v1[r].z, acc[r].z);
            acc[r].w = fmaf(w1, v1[r].w, acc[r].w);
            acc[r].x = fmaf(w2, v2[r].x, acc[r].x);
            acc[r].y = fmaf(w2, v2[r].y, acc[r].y);
            acc[r].z = fmaf(w2, v2[r].z, acc[r].z);
            acc[r].w = fmaf(w2, v2[r].w, acc[r].w);
            acc[r].x = fmaf(w3, v3[r].x, acc[r].x);
            acc[r].y = fmaf(w3, v3[r].y, acc[r].y);
            acc[r].z = fmaf(w3, v3[r].z, acc[r].z);
            acc[r].w = fmaf(w3, v3[r].w, acc[r].w);
        }
    }

    // ---- remainder ----
    for (; e < e1; ++e) {
        int s = eidx[e];
        float sc2 = ssrc[s * HEADS + hd] + sd;
        float el = sc2 > 0.f ? sc2 : NEG_SLOPE * sc2;
        float we = __expf(el);
        wsum += we;
        const float4* sp = (const float4*)(h + (long)s * F + hd * D);
#pragma unroll
        for (int r = 0; r < R; ++r) {
            float4 v = sp[r];
            acc[r].x = fmaf(we, v.x, acc[r].x);
            acc[r].y = fmaf(we, v.y, acc[r].y);
            acc[r].z = fmaf(we, v.z, acc[r].z);
            acc[r].w = fmaf(we, v.w, acc[r].w);
        }
    }

    float inv = 1.f / (wsum + 1e-16f);
    float4* op = (float4*)(out + (long)node * F + hd * D);
#pragma unroll
    for (int r = 0; r < R; ++r) {
        const float4* bp = (const float4*)(bias + hd * D + r * 4);
        float4 b4 = *bp;
        float4 v;
        v.x = acc[r].x * inv + b4.x;
        v.y = acc[r].y * inv + b4.y;
        v.z = acc[r].z * inv + b4.z;
        v.w = acc[r].w * inv + b4.w;
        if (RELU) {
            v.x = v.x > 0.f ? v.x : 0.f;
            v.y = v.y > 0.f ? v.y : 0.f;
            v.z = v.z > 0.f ? v.z : 0.f;
            v.w = v.w > 0.f ? v.w : 0.f;
        }
        op[r] = v;
    }
}

extern "C" void kernel_launch(void* const* d_in, const int* in_sizes, int n_in,
                              void* d_out, int out_size, void* d_ws, size_t ws_size,
                              hipStream_t stream) {
    const float* x   = (const float*)d_in[0];
    const int*   ei  = (const int*)d_in[1];      // [2, N_EDGES] row-major
    const float* W1  = (const float*)d_in[2];
    const float* a1s = (const float*)d_in[3];
    const float* a1d = (const float*)d_in[4];
    const float* b1  = (const float*)d_in[5];
    const float* W2  = (const float*)d_in[6];
    const float* a2s = (const float*)d_in[7];
    const float* a2d = (const float*)d_in[8];
    const float* b2  = (const float*)d_in[9];
    float* out = (float*)d_out;

    const int* src = ei;
    const int* dst = ei + N_EDGES;

    // ---- workspace layout ----
    float* ws = (float*)d_ws;
    float* bufA = ws;                                  // N*128 : h1, later h2 (N*64)
    float* bufB = bufA + (size_t)N_NODES * 128;        // N*128 : out1
    float* ssrc = bufB + (size_t)N_NODES * 128;        // N*8
    float* sdst = ssrc + (size_t)N_NODES * HEADS;      // N*8
    int* counts    = (int*)(sdst + (size_t)N_NODES * HEADS);  // N
    int* row_start = counts + N_NODES;                 // N+1
    int* cursor    = row_start + N_NODES + 1;          // N
    int* bsums     = cursor + N_NODES;                 // 128
    int* eidx      = bsums + 128;                      // N_EDGES

    const int nb_scan = (N_NODES + 1023) / 1024;       // 98

    // ---- CSR build (shared by both layers) ----
    hipMemsetAsync(counts, 0, (size_t)N_NODES * sizeof(int), stream);
    count_kernel<<<(N_EDGES + 255) / 256, 256, 0, stream>>>(dst, counts);
    scan_block_kernel<<<nb_scan, 256, 0, stream>>>(counts, row_start, bsums, N_NODES);
    scan_sums_kernel<<<1, 64, 0, stream>>>(bsums, nb_scan);
    add_offsets_kernel<<<nb_scan, 256, 0, stream>>>(row_start, bsums, cursor, N_NODES);
    scatter_kernel<<<(N_EDGES + 255) / 256, 256, 0, stream>>>(src, dst, cursor, eidx);

    // ---- Layer 1 ----
    gemm_tile_kernel<128, 128><<<(N_NODES + 127) / 128, 256, 0, stream>>>(x, W1, bufA, N_NODES);
    scores_kernel<D1><<<(N_NODES * HEADS + 255) / 256, 256, 0, stream>>>(bufA, a1s, a1d, ssrc, sdst);
    aggregate_kernel<D1, true><<<(N_NODES * HEADS + 255) / 256, 256, 0, stream>>>(
        row_start, eidx, bufA, ssrc, sdst, b1, bufB);

    // ---- Layer 2 ----
    gemm_tile_kernel<128, 64><<<(N_NODES + 255) / 256, 256, 0, stream>>>(bufB, W2, bufA, N_NODES);
    scores_kernel<D2><<<(N_NODES * HEADS + 255) / 256, 256, 0, stream>>>(bufA, a2s, a2d, ssrc, sdst);
    aggregate_kernel<D2, false><<<(N_NODES * HEADS + 255) / 256, 256, 0, stream>>>(
        row_start, eidx, bufA, ssrc, sdst, b2, out);
}